// Round 9
// baseline (172.671 us; speedup 1.0000x reference)
//
#include <hip/hip_runtime.h>
#include <hip/hip_fp16.h>

#define NB 8
#define NC 128
#define NN 1024
#define NG 8
#define NCG 16
#define GEPS 1e-5f

typedef _Float16 half4v __attribute__((ext_vector_type(4)));
typedef _Float16 half8v __attribute__((ext_vector_type(8)));
typedef short short4v __attribute__((ext_vector_type(4)));
typedef float float4v __attribute__((ext_vector_type(4)));
typedef unsigned int uint2v __attribute__((ext_vector_type(2)));

// d_ws layout
#define WS_STATS 0                  // 128 floats (512 B)
#define WS_T     4096               // [64][1024][16] f16 (t*0.5)  = 2 MB
#define WS_V     (4096 + 2097152)   // [64][16][1024] bf16 bits    = 2 MB

// Kernel A: grouped 1x1 conv, computed ONCE per (b,g) pair into global scratch.
// (validated round 7, unchanged)
__global__ __launch_bounds__(256)
void gsa_conv(const float* __restrict__ points, const float* __restrict__ w,
              const float* __restrict__ bias, _Float16* __restrict__ t_glob,
              unsigned short* __restrict__ v_glob)
{
    const int tid  = threadIdx.x;
    const int bid  = blockIdx.x;
    const int pair = bid >> 2;               // b*8 + g
    const int n    = ((bid & 3) << 8) + tid;
    const int g    = pair & 7;

    const float* xg = points + (size_t)pair * NCG * NN;
    const float* wg = w + g * NCG * NCG;

    float x[NCG];
    #pragma unroll
    for (int i = 0; i < NCG; ++i) x[i] = xg[(size_t)i * NN + n];

    _Float16 trow[NCG];
    float ve[NCG];
    #pragma unroll
    for (int o = 0; o < NCG; ++o) {
        float acc = bias[g * NCG + o];
        #pragma unroll
        for (int i = 0; i < NCG; ++i) acc = fmaf(wg[o * NCG + i], x[i], acc);
        trow[o] = (_Float16)(acc * 0.5f);    // folds 1/sqrt(16) into both MFMA operands
        ve[o] = acc > 0.f ? acc : (__expf(acc) - 1.f);
    }

    _Float16* tp = t_glob + ((size_t)pair * NN + n) * NCG;
    *(half8v*)(tp)     = *(const half8v*)&trow[0];
    *(half8v*)(tp + 8) = *(const half8v*)&trow[8];

    unsigned short* vp = v_glob + (size_t)pair * NCG * NN + n;
    #pragma unroll
    for (int o = 0; o < NCG; ++o) {
        const unsigned int u = __builtin_bit_cast(unsigned int, ve[o]);
        vp[(size_t)o * NN] = (unsigned short)((u + 0x8000u) >> 16);
    }
}

// Kernel B: attention, NO LDS, NO barriers, NO cross-wave coupling. Each wave
// owns ONE 16-col m-tile (was 2 in round 7) -> 4096 independent waves = 16
// waves/CU for latency hiding. Inner loop and phase-3 otherwise identical to
// the round-7-validated kernel.
__global__ __launch_bounds__(256)
void gsa_attn(const float* __restrict__ points, const _Float16* __restrict__ t_glob,
              const unsigned short* __restrict__ v_glob, float* __restrict__ y,
              float* __restrict__ stats)
{
    const int tid  = threadIdx.x;
    const int lane = tid & 63;
    const int wv   = tid >> 6;                 // 0..3
    const int tile = blockIdx.x * 4 + wv;      // global m-tile id, [0, 4096)
    const int mt   = tile & 63;                // m-tile within pair
    const int pair = tile >> 6;                // b*8 + g
    const int g    = pair & 7;
    const int b    = pair >> 3;

    const int lq   = lane & 15;
    const int lh   = lane >> 4;                // 0..3
    const int mw   = mt << 4;

    const _Float16* tp = t_glob + (size_t)pair * NN * NCG;
    const unsigned short* vp = v_glob + (size_t)pair * NCG * NN;

    // loop-invariant B fragment: B[k=c][j=m], lane: c=4*lh+j, m=mw+lq
    const half4v bfrag = *(const half4v*)(tp + (size_t)(mw + lq) * NCG + lh * 4);

    float4v acc = {0.f, 0.f, 0.f, 0.f};
    float ssum = 0.f;
    const float4v zz = {0.f, 0.f, 0.f, 0.f};

    const _Float16* ap = tp + (size_t)lq * NCG + lh * 4;          // A[i=n][k=c]
    const unsigned short* vvp = vp + (size_t)lq * NN + lh * 4;    // V A-frag [i=c][k=n]

    #pragma unroll 4
    for (int nt = 0; nt < NN; nt += 16) {
        const half4v afrag  = *(const half4v*)(ap + (size_t)nt * NCG);
        const short4v vfrag = *(const short4v*)(vvp + nt);

        float4v s = __builtin_amdgcn_mfma_f32_16x16x16f16(afrag, bfrag, zz, 0, 0, 0);

        float p[4];
        #pragma unroll
        for (int r = 0; r < 4; ++r) p[r] = __expf(s[r]);
        ssum += (p[0] + p[1]) + (p[2] + p[3]);

        unsigned int pk0, pk1;
        asm("v_cvt_pk_bf16_f32 %0, %1, %2" : "=v"(pk0) : "v"(p[0]), "v"(p[1]));
        asm("v_cvt_pk_bf16_f32 %0, %1, %2" : "=v"(pk1) : "v"(p[2]), "v"(p[3]));
        uint2v u; u[0] = pk0; u[1] = pk1;

        acc = __builtin_amdgcn_mfma_f32_16x16x16bf16_1k(vfrag, __builtin_bit_cast(short4v, u), acc, 0, 0, 0);
    }

    // full column sum (reduce over the 4 lh row-groups)
    ssum += __shfl_xor(ssum, 16); ssum += __shfl_xor(ssum, 32);
    const float rs = 1.0f / ssum;

    // ---- phase 3 (validated): residual + shuffle + unnormalized y + GN partials
    float gs[2] = {0.f, 0.f}, gq[2] = {0.f, 0.f};
    const int m = mw + lq;
    #pragma unroll
    for (int r = 0; r < 4; ++r) {
        const int c = lh * 4 + r;
        const size_t oi = ((size_t)(b * NC) + (c * NG + g)) * NN + m;
        const float val = fmaf(acc[r], rs, points[oi]);
        y[oi] = val;
        gs[r >> 1] += val;            // post-shuffle GN group g' = 2*lh + (r>>1)
        gq[r >> 1] += val * val;
    }
    #pragma unroll
    for (int j = 0; j < 2; ++j) {
        float a = gs[j], q = gq[j];
        #pragma unroll
        for (int off = 1; off <= 8; off <<= 1) {   // reduce over the 16 lq lanes
            a += __shfl_xor(a, off);
            q += __shfl_xor(q, off);
        }
        if (lq == 0) {
            atomicAdd(&stats[(b * NG + lh * 2 + j) * 2 + 0], a);
            atomicAdd(&stats[(b * NG + lh * 2 + j) * 2 + 1], q);
        }
    }
}

// Kernel C: GroupNorm finalize, in place on y, float4. (validated)
__global__ __launch_bounds__(256)
void gsa_norm(const float* __restrict__ stats, const float* __restrict__ gamma,
              const float* __restrict__ beta, float* __restrict__ y)
{
    const int idx = blockIdx.x * 256 + threadIdx.x;
    const size_t base = (size_t)idx * 4;
    const int c = (int)((base >> 10) & (NC - 1));
    const int b = (int)(base >> 17);
    const int gp = c >> 4;

    const float s0 = stats[(b * NG + gp) * 2 + 0];
    const float s1 = stats[(b * NG + gp) * 2 + 1];
    const float inv = 1.0f / (float)(NCG * NN);
    const float mean = s0 * inv;
    const float var = fmaxf(s1 * inv - mean * mean, 0.f);
    const float sc = rsqrtf(var + GEPS) * gamma[c];
    const float sh = fmaf(-mean, sc, beta[c]);

    float4 v = *reinterpret_cast<const float4*>(y + base);
    v.x = fmaf(v.x, sc, sh);
    v.y = fmaf(v.y, sc, sh);
    v.z = fmaf(v.z, sc, sh);
    v.w = fmaf(v.w, sc, sh);
    *reinterpret_cast<float4*>(y + base) = v;
}

extern "C" void kernel_launch(void* const* d_in, const int* in_sizes, int n_in,
                              void* d_out, int out_size, void* d_ws, size_t ws_size,
                              hipStream_t stream)
{
    const float* points = (const float*)d_in[0];
    const float* w      = (const float*)d_in[1];
    const float* bias   = (const float*)d_in[2];
    const float* gamma  = (const float*)d_in[3];
    const float* beta   = (const float*)d_in[4];
    float* y = (float*)d_out;

    char* ws = (char*)d_ws;
    float* stats = (float*)(ws + WS_STATS);
    _Float16* t_glob = (_Float16*)(ws + WS_T);
    unsigned short* v_glob = (unsigned short*)(ws + WS_V);

    hipMemsetAsync(stats, 0, NB * NG * 2 * sizeof(float), stream);
    gsa_conv<<<NB * NG * 4, 256, 0, stream>>>(points, w, bias, t_glob, v_glob);
    gsa_attn<<<NB * NG * 16, 256, 0, stream>>>(points, t_glob, v_glob, y, stats);
    gsa_norm<<<NB * NC * NN / 4 / 256, 256, 0, stream>>>(stats, gamma, beta, y);
}

// Round 10
// 114.332 us; speedup vs baseline: 1.5103x; 1.5103x over previous
//
#include <hip/hip_runtime.h>
#include <hip/hip_fp16.h>

#define NB 8
#define NC 128
#define NN 1024
#define NG 8
#define NCG 16
#define GEPS 1e-5f
#define TPAD 20    // f16 per t-row (16 + 4 pad), row = 40 B, 8-aligned
#define VROW 1032  // bf16 per v-row (1024 + 8 pad), row = 2064 B, 8-aligned

typedef _Float16 half4v __attribute__((ext_vector_type(4)));
typedef _Float16 half8v __attribute__((ext_vector_type(8)));
typedef short short4v __attribute__((ext_vector_type(4)));
typedef float float4v __attribute__((ext_vector_type(4)));
typedef unsigned int uint2v __attribute__((ext_vector_type(2)));

// d_ws layout
#define WS_STATS 0                  // 128 floats (512 B)
#define WS_T     4096               // [64][1024][16] f16 (t*0.5)  = 2 MB
#define WS_V     (4096 + 2097152)   // [64][16][1024] bf16 bits    = 2 MB

// Kernel A: grouped 1x1 conv, computed ONCE per (b,g) pair into global scratch.
// (validated round 7, unchanged)
__global__ __launch_bounds__(256)
void gsa_conv(const float* __restrict__ points, const float* __restrict__ w,
              const float* __restrict__ bias, _Float16* __restrict__ t_glob,
              unsigned short* __restrict__ v_glob)
{
    const int tid  = threadIdx.x;
    const int bid  = blockIdx.x;
    const int pair = bid >> 2;               // b*8 + g
    const int n    = ((bid & 3) << 8) + tid;
    const int g    = pair & 7;

    const float* xg = points + (size_t)pair * NCG * NN;
    const float* wg = w + g * NCG * NCG;

    float x[NCG];
    #pragma unroll
    for (int i = 0; i < NCG; ++i) x[i] = xg[(size_t)i * NN + n];

    _Float16 trow[NCG];
    float ve[NCG];
    #pragma unroll
    for (int o = 0; o < NCG; ++o) {
        float acc = bias[g * NCG + o];
        #pragma unroll
        for (int i = 0; i < NCG; ++i) acc = fmaf(wg[o * NCG + i], x[i], acc);
        trow[o] = (_Float16)(acc * 0.5f);    // folds 1/sqrt(16) into both MFMA operands
        ve[o] = acc > 0.f ? acc : (__expf(acc) - 1.f);
    }

    _Float16* tp = t_glob + ((size_t)pair * NN + n) * NCG;
    *(half8v*)(tp)     = *(const half8v*)&trow[0];
    *(half8v*)(tp + 8) = *(const half8v*)&trow[8];

    unsigned short* vp = v_glob + (size_t)pair * NCG * NN + n;
    #pragma unroll
    for (int o = 0; o < NCG; ++o) {
        const unsigned int u = __builtin_bit_cast(unsigned int, ve[o]);
        vp[(size_t)o * NN] = (unsigned short)((u + 0x8000u) >> 16);
    }
}

// Kernel B: attention. Per (b, g, m-slice of 128): STAGE precomputed t/v from
// global scratch into LDS (replaces round-6's redundant conv phase — the only
// delta from that validated kernel), then the round-5-validated MFMA loop and
// phase-3. 512 WGs x 256 thr, 73 KB LDS -> 2 WGs/CU.
__global__ __launch_bounds__(256)
void gsa_attn(const float* __restrict__ points, const _Float16* __restrict__ t_glob,
              const unsigned short* __restrict__ v_glob, float* __restrict__ y,
              float* __restrict__ stats)
{
    __shared__ __align__(16) _Float16 t_lds[NN][TPAD];        // t * 0.5
    __shared__ __align__(16) unsigned short v_lds[NCG][VROW]; // elu(t) as bf16 bits

    const int tid = threadIdx.x;
    const int bid = blockIdx.x;
    const int ms  = bid & 7;          // m-slice of 128
    const int g   = (bid >> 3) & 7;
    const int b   = bid >> 6;
    const int pair = b * NG + g;

    const _Float16* tp_g = t_glob + (size_t)pair * NN * NCG;
    const unsigned short* vp_g = v_glob + (size_t)pair * NCG * NN;

    // ---- phase 1: stage t and v into LDS (vectorized copies)
    #pragma unroll
    for (int k = 0; k < 4; ++k) {
        const int n = (k << 8) + tid;
        #pragma unroll
        for (int q = 0; q < 4; ++q)
            *(half4v*)&t_lds[n][q * 4] = *(const half4v*)(tp_g + (size_t)n * NCG + q * 4);
    }
    {
        const int j = tid << 2;   // 0..1020
        #pragma unroll
        for (int c = 0; c < NCG; ++c)
            *(short4v*)&v_lds[c][j] = *(const short4v*)(vp_g + (size_t)c * NN + j);
    }
    __syncthreads();

    // ---- phase 2: attention (round-5-validated). Wave owns 32 m-cols.
    const int lane = tid & 63;
    const int wv   = tid >> 6;          // 0..3
    const int lq   = lane & 15;
    const int lh   = lane >> 4;         // 0..3
    const int mw   = (ms << 7) + (wv << 5);

    const half4v bfrag0 = *(const half4v*)&t_lds[mw + lq][lh * 4];
    const half4v bfrag1 = *(const half4v*)&t_lds[mw + 16 + lq][lh * 4];

    float4v acc0 = {0.f, 0.f, 0.f, 0.f}, acc1 = {0.f, 0.f, 0.f, 0.f};
    float ssum0 = 0.f, ssum1 = 0.f;
    const float4v zz = {0.f, 0.f, 0.f, 0.f};

    #pragma unroll 4
    for (int nt = 0; nt < NN; nt += 16) {
        const half4v afrag = *(const half4v*)&t_lds[nt + lq][lh * 4];
        const short4v vfrag = *(const short4v*)&v_lds[lq][nt + lh * 4];

        float4v s0 = __builtin_amdgcn_mfma_f32_16x16x16f16(afrag, bfrag0, zz, 0, 0, 0);
        float4v s1 = __builtin_amdgcn_mfma_f32_16x16x16f16(afrag, bfrag1, zz, 0, 0, 0);

        float p0[4], p1[4];
        #pragma unroll
        for (int r = 0; r < 4; ++r) { p0[r] = __expf(s0[r]); p1[r] = __expf(s1[r]); }
        ssum0 += (p0[0] + p0[1]) + (p0[2] + p0[3]);
        ssum1 += (p1[0] + p1[1]) + (p1[2] + p1[3]);

        unsigned int pk00, pk01, pk10, pk11;
        asm("v_cvt_pk_bf16_f32 %0, %1, %2" : "=v"(pk00) : "v"(p0[0]), "v"(p0[1]));
        asm("v_cvt_pk_bf16_f32 %0, %1, %2" : "=v"(pk01) : "v"(p0[2]), "v"(p0[3]));
        asm("v_cvt_pk_bf16_f32 %0, %1, %2" : "=v"(pk10) : "v"(p1[0]), "v"(p1[1]));
        asm("v_cvt_pk_bf16_f32 %0, %1, %2" : "=v"(pk11) : "v"(p1[2]), "v"(p1[3]));
        uint2v u0; u0[0] = pk00; u0[1] = pk01;
        uint2v u1; u1[0] = pk10; u1[1] = pk11;

        acc0 = __builtin_amdgcn_mfma_f32_16x16x16bf16_1k(vfrag, __builtin_bit_cast(short4v, u0), acc0, 0, 0, 0);
        acc1 = __builtin_amdgcn_mfma_f32_16x16x16bf16_1k(vfrag, __builtin_bit_cast(short4v, u1), acc1, 0, 0, 0);
    }

    ssum0 += __shfl_xor(ssum0, 16); ssum0 += __shfl_xor(ssum0, 32);
    ssum1 += __shfl_xor(ssum1, 16); ssum1 += __shfl_xor(ssum1, 32);
    const float rs0 = 1.0f / ssum0, rs1 = 1.0f / ssum1;

    // ---- phase 3 (validated): residual + shuffle + unnormalized y + GN partials
    float gs[2] = {0.f, 0.f}, gq[2] = {0.f, 0.f};
    #pragma unroll
    for (int mt = 0; mt < 2; ++mt) {
        const float rs = mt ? rs1 : rs0;
        const int m = mw + mt * 16 + lq;
        #pragma unroll
        for (int r = 0; r < 4; ++r) {
            const int c = lh * 4 + r;
            const size_t oi = ((size_t)(b * NC) + (c * NG + g)) * NN + m;
            const float a = mt ? acc1[r] : acc0[r];
            const float val = fmaf(a, rs, points[oi]);
            y[oi] = val;
            gs[r >> 1] += val;            // post-shuffle GN group g' = 2*lh + (r>>1)
            gq[r >> 1] += val * val;
        }
    }
    #pragma unroll
    for (int j = 0; j < 2; ++j) {
        float a = gs[j], q = gq[j];
        #pragma unroll
        for (int off = 1; off <= 8; off <<= 1) {   // reduce over the 16 lq lanes
            a += __shfl_xor(a, off);
            q += __shfl_xor(q, off);
        }
        if (lq == 0) {
            atomicAdd(&stats[(b * NG + lh * 2 + j) * 2 + 0], a);
            atomicAdd(&stats[(b * NG + lh * 2 + j) * 2 + 1], q);
        }
    }
}

// Kernel C: GroupNorm finalize, in place on y, float4. (validated)
__global__ __launch_bounds__(256)
void gsa_norm(const float* __restrict__ stats, const float* __restrict__ gamma,
              const float* __restrict__ beta, float* __restrict__ y)
{
    const int idx = blockIdx.x * 256 + threadIdx.x;
    const size_t base = (size_t)idx * 4;
    const int c = (int)((base >> 10) & (NC - 1));
    const int b = (int)(base >> 17);
    const int gp = c >> 4;

    const float s0 = stats[(b * NG + gp) * 2 + 0];
    const float s1 = stats[(b * NG + gp) * 2 + 1];
    const float inv = 1.0f / (float)(NCG * NN);
    const float mean = s0 * inv;
    const float var = fmaxf(s1 * inv - mean * mean, 0.f);
    const float sc = rsqrtf(var + GEPS) * gamma[c];
    const float sh = fmaf(-mean, sc, beta[c]);

    float4 v = *reinterpret_cast<const float4*>(y + base);
    v.x = fmaf(v.x, sc, sh);
    v.y = fmaf(v.y, sc, sh);
    v.z = fmaf(v.z, sc, sh);
    v.w = fmaf(v.w, sc, sh);
    *reinterpret_cast<float4*>(y + base) = v;
}

extern "C" void kernel_launch(void* const* d_in, const int* in_sizes, int n_in,
                              void* d_out, int out_size, void* d_ws, size_t ws_size,
                              hipStream_t stream)
{
    const float* points = (const float*)d_in[0];
    const float* w      = (const float*)d_in[1];
    const float* bias   = (const float*)d_in[2];
    const float* gamma  = (const float*)d_in[3];
    const float* beta   = (const float*)d_in[4];
    float* y = (float*)d_out;

    char* ws = (char*)d_ws;
    float* stats = (float*)(ws + WS_STATS);
    _Float16* t_glob = (_Float16*)(ws + WS_T);
    unsigned short* v_glob = (unsigned short*)(ws + WS_V);

    hipMemsetAsync(stats, 0, NB * NG * 2 * sizeof(float), stream);
    gsa_conv<<<NB * NG * 4, 256, 0, stream>>>(points, w, bias, t_glob, v_glob);
    gsa_attn<<<NB * NG * 8, 256, 0, stream>>>(points, t_glob, v_glob, y, stats);
    gsa_norm<<<NB * NC * NN / 4 / 256, 256, 0, stream>>>(stats, gamma, beta, y);
}